// Round 1
// baseline (251.268 us; speedup 1.0000x reference)
//
#include <hip/hip_runtime.h>
#include <math.h>

typedef __attribute__((ext_vector_type(8))) short bf16x8;
typedef __attribute__((ext_vector_type(4))) float f32x4;

// ================= compile-time Clebsch-Gordan tables =================
constexpr double cfact(int n){ double r=1.0; for(int i=2;i<=n;++i) r*=(double)i; return r; }
constexpr double csqrt_(double x){ double g=(x>1.0)?x:1.0; for(int i=0;i<100;++i) g=0.5*(g+x/g); return g; }
constexpr double cg_coef_(int l1,int m1,int l2,int m2,int l,int m){
  double pre = csqrt_((double)(2*l+1)*cfact(l1+l2-l)*cfact(l1-l2+l)*cfact(-l1+l2+l)/cfact(l1+l2+l+1));
  pre = pre*csqrt_(cfact(l+m)*cfact(l-m)*cfact(l1-m1)*cfact(l1+m1)*cfact(l2-m2)*cfact(l2+m2));
  double s=0.0;
  for(int k=0;k<=l1+l2-l;++k){
    int d0=k,d1=l1+l2-l-k,d2=l1-m1-k,d3=l2+m2-k,d4=l-l2+m1+k,d5=l-l1-m2+k;
    if(d0<0||d1<0||d2<0||d3<0||d4<0||d5<0) continue;
    double den=cfact(d0)*cfact(d1)*cfact(d2)*cfact(d3)*cfact(d4)*cfact(d5);
    s+=((k&1)?-1.0:1.0)/den;
  }
  return pre*s;
}
struct CGList{ int n; float coef[64]; int mi[64]; int ni[64]; int pi[64]; };
constexpr CGList build_cg(int l1,int l2,int l){
  CGList T{};
  for(int i=0;i<2*l1+1;++i){
    for(int j=0;j<2*l2+1;++j){
      int m1=i-l1, m2=j-l2, m=m1+m2;
      if(m<-l||m>l) continue;
      double c=cg_coef_(l1,m1,l2,m2,l,m);
      if(c>1e-12||c<-1e-12){
        T.coef[T.n]=(float)c; T.mi[T.n]=i; T.ni[T.n]=j; T.pi[T.n]=m+l; T.n++;
      }
    }
  }
  return T;
}

// ================= layout constants =================
__device__ __host__ constexpr int AOFF(int l){ return l==0?0: l==1?16: l==2?64:144; }
__device__ __host__ constexpr int MLs(int l){ return l==0?1024: l==1?1536: l==2?1792:1536; }
__device__ __host__ constexpr int WOFF(int l){ return l==0?0: l==1?16384: l==2?40960:69632; }
__device__ __host__ constexpr int SOFF(int l){ return l==0?0: l==1?1024: l==2?2560:4352; }
__device__ __host__ constexpr int ABASE(int l){ return l==0?0: l==1?65536: l==2?163840:278528; }
__device__ __host__ constexpr size_t MBW(int l){ return l==0?0 : l==1?2097152 : l==2?11534336 : 29884416; }

#define DEVFN __device__ __forceinline__

DEVFN unsigned f2bf2(float x, float y){
  unsigned ux = __float_as_uint(x); ux = (ux + 0x7FFFu + ((ux>>16)&1u)) >> 16;
  unsigned uy = __float_as_uint(y); uy = (uy + 0x7FFFu + ((uy>>16)&1u)) >> 16;
  return (ux & 0xFFFFu) | (uy << 16);
}

template<int L1,int L2,int L>
DEVFN void cg_accum(const float2* F1, const float2* F2, float2* mid){
  constexpr CGList T = build_cg(L1,L2,L);
  #pragma unroll
  for(int e=0;e<T.n;++e){
    const float c = T.coef[e];
    const float2 a = F1[T.mi[e]];
    const float2 b = F2[T.ni[e]];
    float pr = a.x*b.x - a.y*b.y;
    float pim= a.x*b.y + a.y*b.x;
    mid[T.pi[e]].x += c*pr;
    mid[T.pi[e]].y += c*pim;
  }
}

// ===== K1: sum-of-squares only (mid store path disabled: midw=nullptr) =====
template<int L1,int L2,int L,int Q>
DEVFN void k1_body(const float2* __restrict__ acts, int b0, int u, int bh,
                   float& ssa, float& ssb, unsigned* __restrict__ midw){
  constexpr int N1=2*L1+1, N2=2*L2+1, NP=2*L+1, Ml=MLs(L);
  const int t = u>>3, s0 = (u&7)*2;
  unsigned* midq = midw ? (midw + MBW(L) + (size_t)Q*256) : nullptr;
  #pragma unroll 2
  for(int bi=0;bi<8;++bi){
    const int row = bh*8 + bi;
    const float2* arow = acts + row*256;
    float2 F1[N1], F2a[N2], F2b[N2], mida[NP], midb[NP];
    #pragma unroll
    for(int m=0;m<N1;++m) F1[m]=arow[AOFF(L1)+t*N1+m];
    #pragma unroll
    for(int n=0;n<N2;++n){
      F2a[n]=arow[AOFF(L2)+s0*N2+n];
      F2b[n]=arow[AOFF(L2)+(s0+1)*N2+n];
    }
    #pragma unroll
    for(int p=0;p<NP;++p){ mida[p]=make_float2(0.f,0.f); midb[p]=make_float2(0.f,0.f); }
    cg_accum<L1,L2,L>(F1,F2a,mida);
    cg_accum<L1,L2,L>(F1,F2b,midb);
    #pragma unroll
    for(int p=0;p<NP;++p){
      ssa += mida[p].x*mida[p].x + mida[p].y*mida[p].y;
      ssb += midb[p].x*midb[p].x + midb[p].y*midb[p].y;
    }
    if(midq){
      const size_t nrow = (size_t)(b0+row)*NP;
      #pragma unroll
      for(int p=0;p<NP;++p){
        uint2 v; v.x = f2bf2(mida[p].x, mida[p].y); v.y = f2bf2(midb[p].x, midb[p].y);
        ((uint2*)(midq + (nrow+p)*Ml))[u] = v;
      }
    }
  }
}

__global__ __launch_bounds__(256) void k_sumsq(const float* __restrict__ act,
                                               float* __restrict__ sumsq,
                                               unsigned* __restrict__ midw){
  __shared__ float2 acts[16*256];            // 32 KB: 16 act rows
  int bid=blockIdx.x;                        // 23 triples * 128 chunks
  const int order[23] = {22,16,21,18,15,20,13,9,14,8,17,7,12,6,10,3,5,19,2,11,1,4,0};
  int ti = order[bid>>7];
  int b0 = (bid&127)*16;
  const int tid = threadIdx.x;
  {
    const float4* ag = (const float4*)act + (size_t)b0*128;
    float4* as4 = (float4*)acts;
    #pragma unroll
    for(int j=0;j<8;++j) as4[j*256+tid] = ag[j*256+tid];
  }
  __syncthreads();
  const int u = tid & 127, bh = tid >> 7;    // channels (2u,2u+1), b-half bh
  float ssa=0.f, ssb=0.f;
  switch(ti){
    case 0:  k1_body<0,0,0,0>(acts,b0,u,bh,ssa,ssb,midw); break;
    case 1:  k1_body<1,1,0,1>(acts,b0,u,bh,ssa,ssb,midw); break;
    case 2:  k1_body<2,2,0,2>(acts,b0,u,bh,ssa,ssb,midw); break;
    case 3:  k1_body<3,3,0,3>(acts,b0,u,bh,ssa,ssb,midw); break;
    case 4:  k1_body<1,0,1,0>(acts,b0,u,bh,ssa,ssb,midw); break;
    case 5:  k1_body<1,1,1,1>(acts,b0,u,bh,ssa,ssb,midw); break;
    case 6:  k1_body<2,1,1,2>(acts,b0,u,bh,ssa,ssb,midw); break;
    case 7:  k1_body<2,2,1,3>(acts,b0,u,bh,ssa,ssb,midw); break;
    case 8:  k1_body<3,2,1,4>(acts,b0,u,bh,ssa,ssb,midw); break;
    case 9:  k1_body<3,3,1,5>(acts,b0,u,bh,ssa,ssb,midw); break;
    case 10: k1_body<1,1,2,0>(acts,b0,u,bh,ssa,ssb,midw); break;
    case 11: k1_body<2,0,2,1>(acts,b0,u,bh,ssa,ssb,midw); break;
    case 12: k1_body<2,1,2,2>(acts,b0,u,bh,ssa,ssb,midw); break;
    case 13: k1_body<2,2,2,3>(acts,b0,u,bh,ssa,ssb,midw); break;
    case 14: k1_body<3,1,2,4>(acts,b0,u,bh,ssa,ssb,midw); break;
    case 15: k1_body<3,2,2,5>(acts,b0,u,bh,ssa,ssb,midw); break;
    case 16: k1_body<3,3,2,6>(acts,b0,u,bh,ssa,ssb,midw); break;
    case 17: k1_body<2,1,3,0>(acts,b0,u,bh,ssa,ssb,midw); break;
    case 18: k1_body<2,2,3,1>(acts,b0,u,bh,ssa,ssb,midw); break;
    case 19: k1_body<3,0,3,2>(acts,b0,u,bh,ssa,ssb,midw); break;
    case 20: k1_body<3,1,3,3>(acts,b0,u,bh,ssa,ssb,midw); break;
    case 21: k1_body<3,2,3,4>(acts,b0,u,bh,ssa,ssb,midw); break;
    default: k1_body<3,3,3,5>(acts,b0,u,bh,ssa,ssb,midw); break;
  }
  atomicAdd(&sumsq[ti*256 + 2*u],     ssa);
  atomicAdd(&sumsq[ti*256 + 2*u + 1], ssb);
}

// ============ K2: scale + build bf16 A matrices (scale folded into W) =======
__global__ __launch_bounds__(256) void k_buildA(const float* __restrict__ W,
                                                const float* __restrict__ bn,
                                                const float* __restrict__ sumsq,
                                                short* __restrict__ A){
  int idx = blockIdx.x*256 + threadIdx.x;   // 5888 channels
  if(idx>=5888) return;
  int l = (idx<1024)?0 : (idx<2560)?1 : (idx<4352)?2 : 3;
  float divi = (l==0)?(1.f/2048.f) : (l==1)?(1.f/6144.f) : (l==2)?(1.f/10240.f) : (1.f/14336.f);
  float bstd = sqrtf(sumsq[idx]*divi);
  float nstd = 0.5f*(bn[idx]+bstd);
  float s = 1.f/(nstd+1e-5f);
  int c = idx - SOFF(l);
  int Ml = MLs(l);
  const float2* wbase = (const float2*)W + WOFF(l) + c;
  unsigned* Aw = (unsigned*)(A + ABASE(l));   // row pitch = Ml words (2*Ml bf16)
  for(int o=0;o<16;++o){
    float2 w = wbase[(size_t)o*Ml];
    Aw[(size_t)o*Ml + c]      = f2bf2(w.x*s, -w.y*s);
    Aw[(size_t)(o+16)*Ml + c] = f2bf2(w.y*s,  w.x*s);
  }
}

// ======== K3: FUSED recompute-GEMM — no mid HBM traffic ========
// Block = (triple, 8 batches). Per 64-word K-chunk: 256 threads recompute
// the CG mid slice into an LDS B-tile (rows = b_local*NP+p, pitch 68 words
// -> row-rotated banks, b128 reads at conflict-free floor), barrier, then
// 4 waves MFMA it against the triple's A column-slice (L2-hot), barrier.
// f32 partials atomicAdd'ed into the zeroed output (4-7 partials/loc).
template<int L1,int L2,int L,int Q>
DEVFN void kf_body(const float* __restrict__ act, const short* __restrict__ A_l,
                   float* __restrict__ out, int b0, char* smem){
  constexpr int N1=2*L1+1, N2=2*L2+1, NP=2*L+1;
  constexpr int Ml = MLs(L);
  constexpr int S1 = 16*N1;                      // seg1 float2 per batch
  constexpr int SH = (L1==L2)?0:S1;              // seg2 offset in sact
  constexpr int S12 = S1 + ((L1==L2)?0:16*N2);   // float2 per batch staged
  constexpr int F4B = S12/2;                     // float4 per batch
  constexpr int ROWS = 8*NP;                     // valid B-tile rows
  constexpr int NTIL = (ROWS+15)/16;             // 16-row MFMA n-tiles
  constexpr int BP = 68;                         // B-tile pitch (words)
  const int tid = threadIdx.x;
  float2* sa = (float2*)smem;
  unsigned* btile = (unsigned*)(smem + (size_t)8*S12*sizeof(float2));
  // ---- stage only the l1/l2 activation segments (float4 copies) ----
  {
    const float4* actg = (const float4*)act;
    float4* s4 = (float4*)smem;
    for(int i=tid; i<8*F4B; i+=256){
      int lb = i / F4B, e = i - lb*F4B;
      int so = (e < S1/2) ? (AOFF(L1)/2 + e) : (AOFF(L2)/2 + (e - S1/2));
      s4[i] = actg[(size_t)(b0+lb)*128 + so];
    }
  }
  __syncthreads();
  const int lane = tid & 63, w = tid >> 6;
  const int col = lane & 15, quad = lane >> 4;
  const int up = tid & 31, bi = tid >> 5;        // phase1: pair-in-chunk, batch
  const unsigned* Aw = (const unsigned*)A_l;     // 32 rows, pitch Ml words
  f32x4 cR = {0.f,0.f,0.f,0.f};
  f32x4 cI = {0.f,0.f,0.f,0.f};
  #pragma unroll
  for(int cc=0; cc<4; ++cc){
    // ---- phase1: recompute mid for 64 channels x 8 batches -> LDS ----
    {
      const int u = cc*32 + up;
      const int t = u>>3, s0 = (u&7)*2;
      const float2* f1b = sa + bi*S12 + t*N1;
      const float2* f2b = sa + bi*S12 + SH;
      float2 F1[N1], F2a[N2], F2b[N2], mida[NP], midb[NP];
      #pragma unroll
      for(int m=0;m<N1;++m) F1[m]=f1b[m];
      #pragma unroll
      for(int n=0;n<N2;++n){ F2a[n]=f2b[s0*N2+n]; F2b[n]=f2b[(s0+1)*N2+n]; }
      #pragma unroll
      for(int p=0;p<NP;++p){ mida[p]=make_float2(0.f,0.f); midb[p]=make_float2(0.f,0.f); }
      cg_accum<L1,L2,L>(F1,F2a,mida);
      cg_accum<L1,L2,L>(F1,F2b,midb);
      unsigned* bw = btile + 2*up;
      #pragma unroll
      for(int p=0;p<NP;++p){
        const int r = bi*NP + p;
        bw[r*BP]   = f2bf2(mida[p].x, mida[p].y);
        bw[r*BP+1] = f2bf2(midb[p].x, midb[p].y);
      }
    }
    __syncthreads();
    // ---- MFMA: A col-slice [Q*256+cc*64, +64) x B-tile chunk ----
    if(w < NTIL){
      const unsigned* Ab = Aw + Q*256 + cc*64 + quad*4;
      const unsigned* bb = btile + (w*16+col)*BP + quad*4;
      #pragma unroll
      for(int ks=0; ks<4; ++ks){
        bf16x8 A0 = *(const bf16x8*)(Ab + (size_t)col*Ml + ks*16);
        bf16x8 A1 = *(const bf16x8*)(Ab + (size_t)(col+16)*Ml + ks*16);
        bf16x8 b  = *(const bf16x8*)(bb + ks*16);
        cR = __builtin_amdgcn_mfma_f32_16x16x32_bf16(A0, b, cR, 0, 0, 0);
        cI = __builtin_amdgcn_mfma_f32_16x16x32_bf16(A1, b, cI, 0, 0, 0);
      }
    }
    __syncthreads();
  }
  // ---- epilogue: atomic partial-sum into out (pad rows skipped) ----
  if(w < NTIL){
    const int r = w*16 + col;
    if(r < ROWS){
      const int b = b0 + r/NP, p = r - (r/NP)*NP;
      float* ob = out + ((size_t)b*256 + AOFF(L) + p)*2;
      #pragma unroll
      for(int i=0;i<4;++i){
        const int o = quad*4 + i;
        atomicAdd(ob + o*NP*2,     cR[i]);
        atomicAdd(ob + o*NP*2 + 1, cI[i]);
      }
    }
  }
}

__global__ __launch_bounds__(256) void k_fused(const float* __restrict__ act,
                                               const short* __restrict__ A,
                                               float* __restrict__ out){
  __shared__ __align__(16) char smem[29696];   // max: (3,2,3) 12288 sact + 17408 btile
  const int bid = blockIdx.x;                  // 23 triples * 256 chunks
  const int order[23] = {22,16,21,18,15,20,13,9,14,8,17,7,12,6,10,3,5,19,2,11,1,4,0};
  const int ti = order[bid>>8];
  const int b0 = (bid&255)*8;
  switch(ti){
    case 0:  kf_body<0,0,0,0>(act, A+ABASE(0), out, b0, smem); break;
    case 1:  kf_body<1,1,0,1>(act, A+ABASE(0), out, b0, smem); break;
    case 2:  kf_body<2,2,0,2>(act, A+ABASE(0), out, b0, smem); break;
    case 3:  kf_body<3,3,0,3>(act, A+ABASE(0), out, b0, smem); break;
    case 4:  kf_body<1,0,1,0>(act, A+ABASE(1), out, b0, smem); break;
    case 5:  kf_body<1,1,1,1>(act, A+ABASE(1), out, b0, smem); break;
    case 6:  kf_body<2,1,1,2>(act, A+ABASE(1), out, b0, smem); break;
    case 7:  kf_body<2,2,1,3>(act, A+ABASE(1), out, b0, smem); break;
    case 8:  kf_body<3,2,1,4>(act, A+ABASE(1), out, b0, smem); break;
    case 9:  kf_body<3,3,1,5>(act, A+ABASE(1), out, b0, smem); break;
    case 10: kf_body<1,1,2,0>(act, A+ABASE(2), out, b0, smem); break;
    case 11: kf_body<2,0,2,1>(act, A+ABASE(2), out, b0, smem); break;
    case 12: kf_body<2,1,2,2>(act, A+ABASE(2), out, b0, smem); break;
    case 13: kf_body<2,2,2,3>(act, A+ABASE(2), out, b0, smem); break;
    case 14: kf_body<3,1,2,4>(act, A+ABASE(2), out, b0, smem); break;
    case 15: kf_body<3,2,2,5>(act, A+ABASE(2), out, b0, smem); break;
    case 16: kf_body<3,3,2,6>(act, A+ABASE(2), out, b0, smem); break;
    case 17: kf_body<2,1,3,0>(act, A+ABASE(3), out, b0, smem); break;
    case 18: kf_body<2,2,3,1>(act, A+ABASE(3), out, b0, smem); break;
    case 19: kf_body<3,0,3,2>(act, A+ABASE(3), out, b0, smem); break;
    case 20: kf_body<3,1,3,3>(act, A+ABASE(3), out, b0, smem); break;
    case 21: kf_body<3,2,3,4>(act, A+ABASE(3), out, b0, smem); break;
    default: kf_body<3,3,3,5>(act, A+ABASE(3), out, b0, smem); break;
  }
}

// ================= host launch =================
extern "C" void kernel_launch(void* const* d_in, const int* in_sizes, int n_in,
                              void* d_out, int out_size, void* d_ws, size_t ws_size,
                              hipStream_t stream) {
  const float* act = (const float*)d_in[0];   // (2048,256,2) f32
  const float* W   = (const float*)d_in[1];   // (94208,2) f32
  const float* bn  = (const float*)d_in[2];   // (5888,) f32
  float* out = (float*)d_out;                 // (2048,256,2) f32

  float* sumsq = (float*)d_ws;                          // 5888 f32
  short* A     = (short*)((char*)d_ws + 24576);         // 376832 bf16 (754 KB)

  hipMemsetAsync(sumsq, 0, 5888*sizeof(float), stream);
  hipMemsetAsync(out, 0, (size_t)2048*256*2*sizeof(float), stream);
  hipLaunchKernelGGL(k_sumsq,  dim3(23*128), dim3(256), 0, stream, act, sumsq, (unsigned*)nullptr);
  hipLaunchKernelGGL(k_buildA, dim3(23),     dim3(256), 0, stream, W, bn, sumsq, A);
  hipLaunchKernelGGL(k_fused,  dim3(23*256), dim3(256), 0, stream, act, A, out);
}